// Round 1
// baseline (1069.848 us; speedup 1.0000x reference)
//
#include <hip/hip_runtime.h>
#include <hip/hip_bf16.h>
#include <cstdint>
#include <cstddef>

// VarianceAdaptor (FastSpeech2-style) for MI355X.
// R1: correct fp32 implementation, fused conv+ReLU+LN (+linear) kernels.
// Shapes fixed by the problem: B=64, S=512, T=2048, H=F=256, K=3, NBINS=256.

#define HH 256
#define FF 256
#define SS 512
#define BB 64
#define TT 2048

// ---------------- bucket (searchsorted over jnp.linspace(-2,2,255) edges) ----
__device__ __forceinline__ float edge_val(int j) {
    // replicate f32 linspace: start + j*step, endpoint forced to stop
    const float step = 4.0f / 254.0f;  // compile-time f32 division
    if (j == 254) return 2.0f;
    return __fadd_rn(-2.0f, __fmul_rn((float)j, step));
}

__device__ __forceinline__ int bucket256(float v) {
    // count of edges (j=0..254) strictly less than v  == searchsorted 'left'
    int lo = 0, hi = 255;
    while (lo < hi) {
        int mid = (lo + hi) >> 1;      // mid in [0,254]
        if (edge_val(mid) < v) lo = mid + 1; else hi = mid;
    }
    return lo;                          // in [0,255]
}

// ---------------- fused conv1d(K=3) + bias + ReLU + LayerNorm (+ linear) -----
// block: 256 threads = 4 waves; tile: MT=64 sequence positions.
// thread (tf = tid&63, tm = tid>>6): f-cols tf*4..tf*4+3, m-rows tm+4i (i<16).
// Each wave owns complete 256-channel rows for its 16 positions -> LN and the
// final 256->1 dot are wave-level shuffle reductions (no extra LDS/barriers).
constexpr int MT = 64;
constexpr int RW = MT + 2;

template <bool LIN>
__global__ __launch_bounds__(256, 2) void conv_fused(
    const float* __restrict__ in,    // (B,S,256) input rows
    const float* __restrict__ tab,   // optional (256,256) embedding table
    const float* __restrict__ tgt,   // optional (B,S) bucket targets
    const float* __restrict__ w,     // (3,256,256) [k][c][f]
    const float* __restrict__ bias,  // (256)
    const float* __restrict__ g,     // (256) LN gamma
    const float* __restrict__ be,    // (256) LN beta
    const float* __restrict__ lw,    // (256) linear weight (LIN only)
    const float* __restrict__ lb,    // (1)   linear bias   (LIN only)
    const uint8_t* __restrict__ mask,// (B,S) src_mask      (LIN only)
    float* __restrict__ out)         // LIN ? (B,S) : (B,S,256)
{
    __shared__ float tile[RW][HH];
    __shared__ int remb[RW];

    const int tid = threadIdx.x;
    const int b   = blockIdx.x >> 3;          // S/MT = 8 blocks per batch row
    const int s0  = (blockIdx.x & 7) * MT;
    const float* inb = in + (size_t)b * SS * HH;

    if (tab != nullptr && tid < RW) {
        int s = s0 - 1 + tid;
        remb[tid] = (s >= 0 && s < SS) ? bucket256(tgt[b * SS + s]) : 0;
    }
    __syncthreads();

    // stage input tile (halo rows zero-padded at batch boundaries)
    for (int idx = tid; idx < RW * 64; idx += 256) {
        int r  = idx >> 6;
        int c4 = (idx & 63) << 2;
        int s  = s0 - 1 + r;
        float4 v = make_float4(0.f, 0.f, 0.f, 0.f);
        if (s >= 0 && s < SS) {
            v = *(const float4*)(inb + (size_t)s * HH + c4);
            if (tab != nullptr) {
                const float4 tv = *(const float4*)(tab + (size_t)remb[r] * HH + c4);
                v.x += tv.x; v.y += tv.y; v.z += tv.z; v.w += tv.w;
            }
        }
        *(float4*)(&tile[r][c4]) = v;
    }
    __syncthreads();

    const int tf = tid & 63;
    const int tm = tid >> 6;

    float acc[16][4];
    {
        const float4 bv = *(const float4*)(bias + tf * 4);
        #pragma unroll
        for (int i = 0; i < 16; ++i) {
            acc[i][0] = bv.x; acc[i][1] = bv.y; acc[i][2] = bv.z; acc[i][3] = bv.w;
        }
    }

    for (int k = 0; k < 3; ++k) {
        const float* wk = w + (size_t)k * HH * FF + tf * 4;
        for (int c = 0; c < HH; ++c) {
            const float4 wv = *(const float4*)(wk + (size_t)c * FF);
            #pragma unroll
            for (int i = 0; i < 16; ++i) {
                const float xv = tile[tm + 4 * i + k][c];
                acc[i][0] = fmaf(xv, wv.x, acc[i][0]);
                acc[i][1] = fmaf(xv, wv.y, acc[i][1]);
                acc[i][2] = fmaf(xv, wv.z, acc[i][2]);
                acc[i][3] = fmaf(xv, wv.w, acc[i][3]);
            }
        }
    }

    const float4 gv  = *(const float4*)(g + tf * 4);
    const float4 bev = *(const float4*)(be + tf * 4);
    float4 lwv = make_float4(0.f, 0.f, 0.f, 0.f);
    float  lb0 = 0.f;
    if (LIN) { lwv = *(const float4*)(lw + tf * 4); lb0 = lb[0]; }

    #pragma unroll
    for (int i = 0; i < 16; ++i) {
        const int m = tm + 4 * i;
        // ReLU
        const float r0 = fmaxf(acc[i][0], 0.f), r1 = fmaxf(acc[i][1], 0.f);
        const float r2 = fmaxf(acc[i][2], 0.f), r3 = fmaxf(acc[i][3], 0.f);
        // LN over 256 channels spread across the wave (4/lane)
        float s = r0 + r1 + r2 + r3;
        #pragma unroll
        for (int off = 1; off < 64; off <<= 1) s += __shfl_xor(s, off);
        const float mean = s * (1.f / 256.f);
        const float d0 = r0 - mean, d1 = r1 - mean, d2 = r2 - mean, d3 = r3 - mean;
        float ss = d0 * d0 + d1 * d1 + d2 * d2 + d3 * d3;
        #pragma unroll
        for (int off = 1; off < 64; off <<= 1) ss += __shfl_xor(ss, off);
        const float rstd = rsqrtf(ss * (1.f / 256.f) + 1e-5f);
        const float o0 = d0 * rstd * gv.x + bev.x;
        const float o1 = d1 * rstd * gv.y + bev.y;
        const float o2 = d2 * rstd * gv.z + bev.z;
        const float o3 = d3 * rstd * gv.w + bev.w;
        if (LIN) {
            float dv = o0 * lwv.x + o1 * lwv.y + o2 * lwv.z + o3 * lwv.w;
            #pragma unroll
            for (int off = 1; off < 64; off <<= 1) dv += __shfl_xor(dv, off);
            if (tf == 0) {
                const int row = b * SS + s0 + m;
                out[row] = mask[row] ? 0.f : (dv + lb0);
            }
        } else {
            *(float4*)(out + ((size_t)(b * SS + s0 + m)) * FF + tf * 4) =
                make_float4(o0, o1, o2, o3);
        }
    }
}

// ---------------- duration cumsum + d_rounded + mel_len ----------------------
__global__ void dur_kernel(const int* __restrict__ dur, int* __restrict__ cum,
                           float* __restrict__ drnd, float* __restrict__ mlen) {
    __shared__ int sb[SS];
    const int b = blockIdx.x, t = threadIdx.x;
    const int v = dur[b * SS + t];
    drnd[b * SS + t] = (float)v;
    sb[t] = v;
    __syncthreads();
    for (int off = 1; off < SS; off <<= 1) {
        const int add = (t >= off) ? sb[t - off] : 0;
        __syncthreads();
        sb[t] += add;
        __syncthreads();
    }
    cum[b * SS + t] = sb[t];
    if (t == SS - 1) mlen[b] = (float)sb[t];
}

// ---------------- length regulator: mel[b,t,:] = x3[b,idx(t),:] or 0 ---------
// x3 recomputed on the fly: x + p_table[bucket(pitch)] + e_table[bucket(energy)]
__global__ __launch_bounds__(256) void gather_kernel(
    const float* __restrict__ x,
    const float* __restrict__ ptab, const float* __restrict__ pt,
    const float* __restrict__ etab, const float* __restrict__ et,
    const int* __restrict__ cum, float* __restrict__ mel)
{
    const int row  = blockIdx.x * 4 + (threadIdx.x >> 6);   // b*T + t
    const int lane = threadIdx.x & 63;
    const int b = row >> 11;                                // T = 2048
    const int t = row & (TT - 1);
    const int* cb = cum + b * SS;
    const int ml = cb[SS - 1];
    float4 v = make_float4(0.f, 0.f, 0.f, 0.f);
    if (t < ml) {
        int lo = 0, hi = SS;                                // searchsorted 'right'
        while (lo < hi) { int mid = (lo + hi) >> 1; if (cb[mid] <= t) lo = mid + 1; else hi = mid; }
        const int idx = min(lo, SS - 1);
        const size_t src = ((size_t)b * SS + idx) * HH + lane * 4;
        v = *(const float4*)(x + src);
        const int pb = bucket256(pt[b * SS + idx]);
        const int eb = bucket256(et[b * SS + idx]);
        const float4 pv = *(const float4*)(ptab + (size_t)pb * HH + lane * 4);
        const float4 ev = *(const float4*)(etab + (size_t)eb * HH + lane * 4);
        v.x += pv.x + ev.x; v.y += pv.y + ev.y; v.z += pv.z + ev.z; v.w += pv.w + ev.w;
    }
    *(float4*)(mel + (size_t)row * HH + lane * 4) = v;
}

// ---------------- launch -----------------------------------------------------
extern "C" void kernel_launch(void* const* d_in, const int* in_sizes, int n_in,
                              void* d_out, int out_size, void* d_ws, size_t ws_size,
                              hipStream_t stream) {
    (void)in_sizes; (void)n_in; (void)out_size; (void)ws_size;

    const float*   x      = (const float*)d_in[0];
    const float*   pitch  = (const float*)d_in[1];
    const float*   energy = (const float*)d_in[2];
    const uint8_t* mask   = (const uint8_t*)d_in[3];
    const int*     dur    = (const int*)d_in[4];
    // predictor param bases: d=6, p=16, e=26 ; each: w1,b1,g1,be1,w2,b2,g2,be2,lw,lb
    const float* ptab = (const float*)d_in[36];
    const float* etab = (const float*)d_in[37];

    float* out = (float*)d_out;
    const size_t N_MEL = (size_t)BB * TT * HH;
    float* out_p  = out + N_MEL;                // p_pred   (B,S)
    float* out_e  = out_p + (size_t)BB * SS;    // e_pred
    float* out_ld = out_e + (size_t)BB * SS;    // log_d_pred
    float* out_dr = out_ld + (size_t)BB * SS;   // d_rounded (as f32)
    float* out_ml = out_dr + (size_t)BB * SS;   // mel_len   (as f32)

    float* h1 = (float*)d_ws;                            // (B,S,256)
    int*   cum = (int*)(h1 + (size_t)BB * SS * FF);      // (B,S)

    const int convGrid = BB * (SS / MT);                 // 512
    const dim3 blk(256);

    struct Pred { int base; const float* in; const float* tab; const float* tgt; float* out; };
    const Pred preds[3] = {
        {6,  x, nullptr, nullptr, out_ld},   // duration predictor on x
        {16, x, nullptr, nullptr, out_p},    // pitch predictor on x
        {26, x, ptab,    pitch,   out_e},    // energy predictor on x + p_emb
    };

    for (int p = 0; p < 3; ++p) {
        const Pred& P = preds[p];
        const float* w1  = (const float*)d_in[P.base + 0];
        const float* b1  = (const float*)d_in[P.base + 1];
        const float* g1  = (const float*)d_in[P.base + 2];
        const float* be1 = (const float*)d_in[P.base + 3];
        const float* w2  = (const float*)d_in[P.base + 4];
        const float* b2  = (const float*)d_in[P.base + 5];
        const float* g2  = (const float*)d_in[P.base + 6];
        const float* be2 = (const float*)d_in[P.base + 7];
        const float* lw  = (const float*)d_in[P.base + 8];
        const float* lb  = (const float*)d_in[P.base + 9];

        conv_fused<false><<<convGrid, blk, 0, stream>>>(
            P.in, P.tab, P.tgt, w1, b1, g1, be1, nullptr, nullptr, nullptr, h1);
        conv_fused<true><<<convGrid, blk, 0, stream>>>(
            h1, nullptr, nullptr, w2, b2, g2, be2, lw, lb, mask, P.out);
    }

    dur_kernel<<<BB, SS, 0, stream>>>(dur, cum, out_dr, out_ml);
    gather_kernel<<<(BB * TT) / 4, blk, 0, stream>>>(x, ptab, pitch, etab, energy, cum, out);
}

// Round 2
// 271.597 us; speedup vs baseline: 3.9391x; 3.9391x over previous
//
#include <hip/hip_runtime.h>
#include <cstdint>
#include <cstddef>

// VarianceAdaptor — R2: bf16 MFMA convs (16x16x32), fused ReLU+LN(+linear),
// XOR-swizzled LDS X-tile, W pre-transposed to [k][f][c] bf16.
// B=64, S=512, T=2048, H=F=256, K=3, NBINS=256.

#define HH 256
#define SS 512
#define BB 64
#define TT 2048

typedef __bf16 bf16;
typedef __attribute__((ext_vector_type(8))) __bf16 bf16x8;
typedef __attribute__((ext_vector_type(4))) __bf16 bf16x4;
typedef __attribute__((ext_vector_type(4))) float f32x4;

// swizzled halfword index into a [rows][256] bf16 LDS tile (row stride 512B).
// XOR of byte-bit4 with row&7 -> spreads the 512B-stride column across 8 banks.
__device__ __forceinline__ int swz(int r, int c) { return (r * HH + c) ^ ((r & 7) << 3); }

// ---------------- bucket (searchsorted over jnp.linspace(-2,2,255) edges) ----
__device__ __forceinline__ float edge_val(int j) {
    const float step = 4.0f / 254.0f;
    if (j == 254) return 2.0f;
    return __fadd_rn(-2.0f, __fmul_rn((float)j, step));
}
__device__ __forceinline__ int bucket256(float v) {
    int lo = 0, hi = 255;
    while (lo < hi) {
        int mid = (lo + hi) >> 1;
        if (edge_val(mid) < v) lo = mid + 1; else hi = mid;
    }
    return lo;
}

// ---------------- weight transpose+cast: w[k][c][f] f32 -> wt[k][f][c] bf16 --
__global__ void wt_kernel(const float* __restrict__ w0, const float* __restrict__ w1,
                          const float* __restrict__ w2, const float* __restrict__ w3,
                          const float* __restrict__ w4, const float* __restrict__ w5,
                          bf16* __restrict__ wt) {
    const int cv = blockIdx.x / 3, k = blockIdx.x % 3;
    const float* wsel[6] = {w0, w1, w2, w3, w4, w5};
    const float* wk = wsel[cv] + (size_t)k * HH * HH;          // [c][f]
    const int f = threadIdx.x;
    bf16* o = wt + ((size_t)cv * 3 + k) * HH * HH + (size_t)f * HH;
    for (int c0 = 0; c0 < HH; c0 += 8) {
        bf16x8 v;
        #pragma unroll
        for (int j = 0; j < 8; ++j) v[j] = (bf16)wk[(size_t)(c0 + j) * HH + f];
        *(bf16x8*)(o + c0) = v;
    }
}

// ---------------- fused MFMA conv1d(K=3) + bias + ReLU + LN (+ linear) -------
// 256 threads = 4 waves; tile M=64 rows; wave w owns cols [64w, 64w+64).
// Per wave: 4x4 frags of 16x16, K-loop = 3 shifts x 8 steps of K=32.
template <bool LIN, bool EMB, bool B16>
__global__ __launch_bounds__(256, 2) void conv_mfma(
    const void* __restrict__ in,     // (B,S,256) f32 (or bf16 if B16)
    const float* __restrict__ tab,   // (256,256) embedding table (EMB)
    const float* __restrict__ tgt,   // (B,S) bucket targets      (EMB)
    const bf16* __restrict__ wt,     // (3,256,256) [k][f][c] bf16
    const float* __restrict__ bias,  // (256)
    const float* __restrict__ g,     // (256) LN gamma
    const float* __restrict__ be,    // (256) LN beta
    const float* __restrict__ lw,    // (256) linear weight (LIN)
    const float* __restrict__ lb,    // (1)   linear bias   (LIN)
    const uint8_t* __restrict__ mask,// (B,S)               (LIN)
    void* __restrict__ out)          // LIN ? f32 (B,S) : bf16 (B,S,256)
{
    __shared__ alignas(16) bf16 tile[66 * HH];
    __shared__ float red_s[64][4], red_q[64][4];
    __shared__ float ln_m[64], ln_r[64];
    __shared__ int remb[66];

    const int tid = threadIdx.x;
    const int b   = blockIdx.x >> 3;
    const int s0  = (blockIdx.x & 7) * 64;

    if (EMB) {
        if (tid < 66) {
            int s = s0 - 1 + tid;
            remb[tid] = (s >= 0 && s < SS) ? bucket256(tgt[b * SS + s]) : 0;
        }
        __syncthreads();
    }

    if (!B16) {
        const float* inb = (const float*)in + (size_t)b * SS * HH;
        for (int idx = tid; idx < 66 * 64; idx += 256) {
            const int r = idx >> 6, c4 = (idx & 63) << 2;
            const int s = s0 - 1 + r;
            float4 v = make_float4(0.f, 0.f, 0.f, 0.f);
            if (s >= 0 && s < SS) {
                v = *(const float4*)(inb + (size_t)s * HH + c4);
                if (EMB) {
                    const float4 tv = *(const float4*)(tab + (size_t)remb[r] * HH + c4);
                    v.x += tv.x; v.y += tv.y; v.z += tv.z; v.w += tv.w;
                }
            }
            bf16x4 bv = {(bf16)v.x, (bf16)v.y, (bf16)v.z, (bf16)v.w};
            *(bf16x4*)&tile[swz(r, c4)] = bv;
        }
    } else {
        const bf16* inb = (const bf16*)in + (size_t)b * SS * HH;
        for (int idx = tid; idx < 66 * 32; idx += 256) {
            const int r = idx >> 5, c8 = (idx & 31) << 3;
            const int s = s0 - 1 + r;
            bf16x8 v = {};
            if (s >= 0 && s < SS) v = *(const bf16x8*)(inb + (size_t)s * HH + c8);
            *(bf16x8*)&tile[swz(r, c8)] = v;
        }
    }
    __syncthreads();

    const int lane = tid & 63;
    const int wv   = tid >> 6;
    const int ln15 = lane & 15;
    const int g8   = (lane >> 4) << 3;     // k-slice element offset (0/8/16/24)

    f32x4 acc[4][4];
    #pragma unroll
    for (int nf = 0; nf < 4; ++nf) {
        const float bv = bias[wv * 64 + nf * 16 + ln15];
        #pragma unroll
        for (int mf = 0; mf < 4; ++mf) acc[mf][nf] = f32x4{bv, bv, bv, bv};
    }

    #pragma unroll 1
    for (int k = 0; k < 3; ++k) {
        const bf16* bp0 = wt + (size_t)k * HH * HH + (size_t)(wv * 64 + ln15) * HH + g8;
        #pragma unroll 2
        for (int kc = 0; kc < HH; kc += 32) {
            bf16x8 a[4], bb[4];
            #pragma unroll
            for (int mf = 0; mf < 4; ++mf)
                a[mf] = *(const bf16x8*)&tile[swz(16 * mf + ln15 + k, kc + g8)];
            #pragma unroll
            for (int nf = 0; nf < 4; ++nf)
                bb[nf] = *(const bf16x8*)(bp0 + (size_t)nf * 16 * HH + kc);
            #pragma unroll
            for (int mf = 0; mf < 4; ++mf)
                #pragma unroll
                for (int nf = 0; nf < 4; ++nf)
                    acc[mf][nf] = __builtin_amdgcn_mfma_f32_16x16x32_bf16(
                        a[mf], bb[nf], acc[mf][nf], 0, 0, 0);
        }
    }

    // ReLU in place
    #pragma unroll
    for (int mf = 0; mf < 4; ++mf)
        #pragma unroll
        for (int nf = 0; nf < 4; ++nf)
            #pragma unroll
            for (int i = 0; i < 4; ++i)
                acc[mf][nf][i] = fmaxf(acc[mf][nf][i], 0.f);

    // LN partials: per (mf,i) each lane sums its 4 cols, reduce across 16 lanes.
    #pragma unroll
    for (int mf = 0; mf < 4; ++mf) {
        #pragma unroll
        for (int i = 0; i < 4; ++i) {
            float s = acc[mf][0][i] + acc[mf][1][i] + acc[mf][2][i] + acc[mf][3][i];
            float q = acc[mf][0][i] * acc[mf][0][i] + acc[mf][1][i] * acc[mf][1][i] +
                      acc[mf][2][i] * acc[mf][2][i] + acc[mf][3][i] * acc[mf][3][i];
            #pragma unroll
            for (int off = 1; off < 16; off <<= 1) {
                s += __shfl_xor(s, off);
                q += __shfl_xor(q, off);
            }
            if (ln15 == 0) {
                const int row = 16 * mf + (lane >> 4) * 4 + i;
                red_s[row][wv] = s;
                red_q[row][wv] = q;
            }
        }
    }
    __syncthreads();
    if (tid < 64) {
        const float s = red_s[tid][0] + red_s[tid][1] + red_s[tid][2] + red_s[tid][3];
        const float q = red_q[tid][0] + red_q[tid][1] + red_q[tid][2] + red_q[tid][3];
        const float mean = s * (1.f / 256.f);
        const float var  = q * (1.f / 256.f) - mean * mean;
        ln_m[tid] = mean;
        ln_r[tid] = rsqrtf(var + 1e-5f);
    }
    __syncthreads();

    float gv[4], bev[4];
    #pragma unroll
    for (int nf = 0; nf < 4; ++nf) {
        const int col = wv * 64 + nf * 16 + ln15;
        gv[nf] = g[col];
        bev[nf] = be[col];
    }

    if (!LIN) {
        bf16* ob = (bf16*)out + ((size_t)(b * SS + s0)) * HH;
        #pragma unroll
        for (int mf = 0; mf < 4; ++mf) {
            #pragma unroll
            for (int i = 0; i < 4; ++i) {
                const int row = 16 * mf + (lane >> 4) * 4 + i;
                const float mean = ln_m[row], rs = ln_r[row];
                #pragma unroll
                for (int nf = 0; nf < 4; ++nf) {
                    const float o = (acc[mf][nf][i] - mean) * rs * gv[nf] + bev[nf];
                    ob[(size_t)row * HH + wv * 64 + nf * 16 + ln15] = (bf16)o;
                }
            }
        }
    } else {
        float lwv[4];
        #pragma unroll
        for (int nf = 0; nf < 4; ++nf) lwv[nf] = lw[wv * 64 + nf * 16 + ln15];
        const float lb0 = lb[0];
        #pragma unroll
        for (int mf = 0; mf < 4; ++mf) {
            #pragma unroll
            for (int i = 0; i < 4; ++i) {
                const int row = 16 * mf + (lane >> 4) * 4 + i;
                const float mean = ln_m[row], rs = ln_r[row];
                float t = 0.f;
                #pragma unroll
                for (int nf = 0; nf < 4; ++nf)
                    t += ((acc[mf][nf][i] - mean) * rs * gv[nf] + bev[nf]) * lwv[nf];
                #pragma unroll
                for (int off = 1; off < 16; off <<= 1) t += __shfl_xor(t, off);
                if (ln15 == 0) red_s[row][wv] = t;
            }
        }
        __syncthreads();
        if (tid < 64) {
            const int gr = b * SS + s0 + tid;
            const float dv = red_s[tid][0] + red_s[tid][1] + red_s[tid][2] + red_s[tid][3] + lb0;
            ((float*)out)[gr] = mask[gr] ? 0.f : dv;
        }
    }
}

// ---------------- duration cumsum + d_rounded + mel_len ----------------------
__global__ void dur_kernel(const int* __restrict__ dur, int* __restrict__ cum,
                           float* __restrict__ drnd, float* __restrict__ mlen) {
    __shared__ int sb[SS];
    const int b = blockIdx.x, t = threadIdx.x;
    const int v = dur[b * SS + t];
    drnd[b * SS + t] = (float)v;
    sb[t] = v;
    __syncthreads();
    for (int off = 1; off < SS; off <<= 1) {
        const int add = (t >= off) ? sb[t - off] : 0;
        __syncthreads();
        sb[t] += add;
        __syncthreads();
    }
    cum[b * SS + t] = sb[t];
    if (t == SS - 1) mlen[b] = (float)sb[t];
}

// ---------------- length regulator (f32 path, exact) -------------------------
__global__ __launch_bounds__(256) void gather_kernel(
    const float* __restrict__ x,
    const float* __restrict__ ptab, const float* __restrict__ pt,
    const float* __restrict__ etab, const float* __restrict__ et,
    const int* __restrict__ cum, float* __restrict__ mel)
{
    const int row  = blockIdx.x * 4 + (threadIdx.x >> 6);   // b*T + t
    const int lane = threadIdx.x & 63;
    const int b = row >> 11;
    const int t = row & (TT - 1);
    const int* cb = cum + b * SS;
    const int ml = cb[SS - 1];
    float4 v = make_float4(0.f, 0.f, 0.f, 0.f);
    if (t < ml) {
        int lo = 0, hi = SS;
        while (lo < hi) { int mid = (lo + hi) >> 1; if (cb[mid] <= t) lo = mid + 1; else hi = mid; }
        const int idx = min(lo, SS - 1);
        const size_t src = ((size_t)b * SS + idx) * HH + lane * 4;
        v = *(const float4*)(x + src);
        const int pb = bucket256(pt[b * SS + idx]);
        const int eb = bucket256(et[b * SS + idx]);
        const float4 pv = *(const float4*)(ptab + (size_t)pb * HH + lane * 4);
        const float4 ev = *(const float4*)(etab + (size_t)eb * HH + lane * 4);
        v.x += pv.x + ev.x; v.y += pv.y + ev.y; v.z += pv.z + ev.z; v.w += pv.w + ev.w;
    }
    *(float4*)(mel + (size_t)row * HH + lane * 4) = v;
}

// ---------------- launch -----------------------------------------------------
extern "C" void kernel_launch(void* const* d_in, const int* in_sizes, int n_in,
                              void* d_out, int out_size, void* d_ws, size_t ws_size,
                              hipStream_t stream) {
    (void)in_sizes; (void)n_in; (void)out_size; (void)ws_size;

    const float*   x      = (const float*)d_in[0];
    const float*   pitch  = (const float*)d_in[1];
    const float*   energy = (const float*)d_in[2];
    const uint8_t* mask   = (const uint8_t*)d_in[3];
    const int*     dur    = (const int*)d_in[4];
    const float*   ptab   = (const float*)d_in[36];
    const float*   etab   = (const float*)d_in[37];

    float* out = (float*)d_out;
    const size_t N_MEL = (size_t)BB * TT * HH;
    float* out_p  = out + N_MEL;
    float* out_e  = out_p + (size_t)BB * SS;
    float* out_ld = out_e + (size_t)BB * SS;
    float* out_dr = out_ld + (size_t)BB * SS;
    float* out_ml = out_dr + (size_t)BB * SS;

    // ws: h1 (bf16 B*S*256 = 16MB) | wt (6*3*256*256 bf16 = 2.25MB) | cum
    bf16* h1  = (bf16*)d_ws;
    bf16* wtb = h1 + (size_t)BB * SS * HH;
    int*  cum = (int*)(wtb + (size_t)6 * 3 * HH * HH);

    // transpose+cast all 6 conv weights (grid 18, trivial)
    wt_kernel<<<18, 256, 0, stream>>>(
        (const float*)d_in[6],  (const float*)d_in[10],   // d: w1, w2
        (const float*)d_in[16], (const float*)d_in[20],   // p: w1, w2
        (const float*)d_in[26], (const float*)d_in[30],   // e: w1, w2
        wtb);

    const int convGrid = BB * (SS / 64);   // 512
    const dim3 blk(256);
    const size_t WSZ = (size_t)3 * HH * HH;

    struct Pred { int base; int wti; const float* tab; const float* tgt; float* out; };
    const Pred preds[3] = {
        {6,  0, nullptr, nullptr, out_ld},   // duration
        {16, 2, nullptr, nullptr, out_p},    // pitch
        {26, 4, ptab,    pitch,   out_e},    // energy (input = x + p_emb)
    };

    for (int p = 0; p < 3; ++p) {
        const Pred& P = preds[p];
        const float* b1  = (const float*)d_in[P.base + 1];
        const float* g1  = (const float*)d_in[P.base + 2];
        const float* be1 = (const float*)d_in[P.base + 3];
        const float* b2  = (const float*)d_in[P.base + 5];
        const float* g2  = (const float*)d_in[P.base + 6];
        const float* be2 = (const float*)d_in[P.base + 7];
        const float* lw  = (const float*)d_in[P.base + 8];
        const float* lb  = (const float*)d_in[P.base + 9];

        if (P.tab) {
            conv_mfma<false, true, false><<<convGrid, blk, 0, stream>>>(
                x, P.tab, P.tgt, wtb + P.wti * WSZ, b1, g1, be1,
                nullptr, nullptr, nullptr, h1);
        } else {
            conv_mfma<false, false, false><<<convGrid, blk, 0, stream>>>(
                x, nullptr, nullptr, wtb + P.wti * WSZ, b1, g1, be1,
                nullptr, nullptr, nullptr, h1);
        }
        conv_mfma<true, false, true><<<convGrid, blk, 0, stream>>>(
            h1, nullptr, nullptr, wtb + (P.wti + 1) * WSZ, b2, g2, be2,
            lw, lb, mask, P.out);
    }

    dur_kernel<<<BB, SS, 0, stream>>>(dur, cum, out_dr, out_ml);
    gather_kernel<<<(BB * TT) / 4, blk, 0, stream>>>(x, ptab, pitch, etab, energy, cum, out);
}

// Round 3
// 165.823 us; speedup vs baseline: 6.4517x; 1.6379x over previous
//
#include <hip/hip_runtime.h>
#include <cstdint>
#include <cstddef>

// VarianceAdaptor — R3: merged 3-predictor MFMA conv dispatches,
// fragment-packed bf16 weights (coalesced B loads), h1 in mel region.
// B=64, S=512, T=2048, H=F=256, K=3, NBINS=256.

#define HH 256
#define SS 512
#define BB 64
#define TT 2048

typedef __bf16 bf16;
typedef __attribute__((ext_vector_type(8))) __bf16 bf16x8;
typedef __attribute__((ext_vector_type(4))) __bf16 bf16x4;
typedef __attribute__((ext_vector_type(4))) float f32x4;

static constexpr size_t WSZ   = (size_t)3 * HH * HH;        // elems per conv weight
static constexpr size_t H1SZ  = (size_t)BB * SS * HH;       // elems per h1 buffer

// swizzled halfword index into a [rows][256] bf16 LDS tile (row stride 512B).
__device__ __forceinline__ int swz(int r, int c) { return (r * HH + c) ^ ((r & 7) << 3); }

// ---------------- bucket (searchsorted over jnp.linspace(-2,2,255) edges) ----
__device__ __forceinline__ float edge_val(int j) {
    const float step = 4.0f / 254.0f;
    if (j == 254) return 2.0f;
    return __fadd_rn(-2.0f, __fmul_rn((float)j, step));
}
__device__ __forceinline__ int bucket256(float v) {
    int lo = 0, hi = 255;
    while (lo < hi) {
        int mid = (lo + hi) >> 1;
        if (edge_val(mid) < v) lo = mid + 1; else hi = mid;
    }
    return lo;
}

// ------------- weight pack: w[k][c][f] f32 -> wp[k][fb][kcb][lane][8] bf16 ---
// B-frag for mfma_16x16x32: lane l holds B[col = fb*16 + (l&15)]
//                                  [c   = kcb*32 + (l>>4)*8 + j], j=0..7
__global__ void wt_pack(const float* __restrict__ w0, const float* __restrict__ w1,
                        const float* __restrict__ w2, const float* __restrict__ w3,
                        const float* __restrict__ w4, const float* __restrict__ w5,
                        bf16* __restrict__ wp) {
    const int cv = blockIdx.x / 3, k = blockIdx.x % 3;
    const float* wsel[6] = {w0, w1, w2, w3, w4, w5};
    const float* wk = wsel[cv] + (size_t)k * HH * HH;   // [c][f]
    bf16* o = wp + ((size_t)(cv * 3 + k)) * HH * HH;
    for (int fb = 0; fb < 16; ++fb) {
        #pragma unroll
        for (int h = 0; h < 2; ++h) {
            const int idx  = threadIdx.x + 256 * h;     // 0..511
            const int kcb  = idx >> 6, lane = idx & 63;
            const int f    = fb * 16 + (lane & 15);
            const int c0   = kcb * 32 + (lane >> 4) * 8;
            bf16x8 v;
            #pragma unroll
            for (int j = 0; j < 8; ++j) v[j] = (bf16)wk[(size_t)(c0 + j) * HH + f];
            *(bf16x8*)(o + (((size_t)fb * 8 + kcb) * 64 + lane) * 8) = v;
        }
    }
}

// ---------------- merged fused conv (3 predictors in one grid) ---------------
struct Args3 {
    const float* bias[3];
    const float* g[3];
    const float* be[3];
    const float* lw[3];
    const float* lb[3];
    float*       out[3];
};

// grid = 3*512; 256 threads = 4 waves; tile M=64 rows; wave w: cols [64w,64w+64)
template <bool LIN>
__global__ __launch_bounds__(256, 3) void conv_all(
    const void* __restrict__ in,      // !LIN: x f32 ; LIN: h1 base bf16
    const float* __restrict__ tab,    // p_table (used by pred 2, !LIN)
    const float* __restrict__ tgt,    // pitch_target
    const bf16* __restrict__ wpk,     // packed weights, 6 convs
    Args3 args,
    bf16* __restrict__ h1out,         // !LIN output base
    const uint8_t* __restrict__ mask) // LIN only
{
    __shared__ alignas(16) bf16 tile[66 * HH];
    __shared__ float red_s[64][4], red_q[64][4];
    __shared__ float ln_m[64], ln_r[64];
    __shared__ int remb[66];

    const int tid    = threadIdx.x;
    const int pred   = blockIdx.x >> 9;
    const int within = blockIdx.x & 511;
    const int b      = within >> 3;
    const int s0     = (within & 7) * 64;
    const bool emb   = (!LIN) && (pred == 2);

    if (emb) {
        if (tid < 66) {
            int s = s0 - 1 + tid;
            remb[tid] = (s >= 0 && s < SS) ? bucket256(tgt[b * SS + s]) : 0;
        }
        __syncthreads();
    }

    if (!LIN) {
        const float* inb = (const float*)in + (size_t)b * SS * HH;
        for (int idx = tid; idx < 66 * 64; idx += 256) {
            const int r = idx >> 6, c4 = (idx & 63) << 2;
            const int s = s0 - 1 + r;
            float4 v = make_float4(0.f, 0.f, 0.f, 0.f);
            if (s >= 0 && s < SS) {
                v = *(const float4*)(inb + (size_t)s * HH + c4);
                if (emb) {
                    const float4 tv = *(const float4*)(tab + (size_t)remb[r] * HH + c4);
                    v.x += tv.x; v.y += tv.y; v.z += tv.z; v.w += tv.w;
                }
            }
            bf16x4 bv = {(bf16)v.x, (bf16)v.y, (bf16)v.z, (bf16)v.w};
            *(bf16x4*)&tile[swz(r, c4)] = bv;
        }
    } else {
        const bf16* inb = (const bf16*)in + (size_t)pred * H1SZ + (size_t)b * SS * HH;
        for (int idx = tid; idx < 66 * 32; idx += 256) {
            const int r = idx >> 5, c8 = (idx & 31) << 3;
            const int s = s0 - 1 + r;
            bf16x8 v = {};
            if (s >= 0 && s < SS) v = *(const bf16x8*)(inb + (size_t)s * HH + c8);
            *(bf16x8*)&tile[swz(r, c8)] = v;
        }
    }
    __syncthreads();

    const int lane = tid & 63;
    const int wv   = tid >> 6;
    const int ln15 = lane & 15;
    const int g8   = (lane >> 4) << 3;

    const bf16* wt = wpk + (size_t)(pred * 2 + (LIN ? 1 : 0)) * WSZ;

    f32x4 acc[4][4];
    #pragma unroll
    for (int nf = 0; nf < 4; ++nf) {
        const float bv = args.bias[pred][wv * 64 + nf * 16 + ln15];
        #pragma unroll
        for (int mf = 0; mf < 4; ++mf) acc[mf][nf] = f32x4{bv, bv, bv, bv};
    }

    #pragma unroll 1
    for (int k = 0; k < 3; ++k) {
        // packed base for this wave: [k][fb = wv*4 + nf][kcb][lane][8]
        const bf16* wpw = wt + (((size_t)k * 16 + wv * 4) * 8) * 512 + (size_t)lane * 8;
        #pragma unroll 2
        for (int kcb = 0; kcb < 8; ++kcb) {
            const int kc = kcb * 32;
            bf16x8 a[4], bb[4];
            #pragma unroll
            for (int mf = 0; mf < 4; ++mf)
                a[mf] = *(const bf16x8*)&tile[swz(16 * mf + ln15 + k, kc + g8)];
            #pragma unroll
            for (int nf = 0; nf < 4; ++nf)
                bb[nf] = *(const bf16x8*)(wpw + ((size_t)nf * 8 + kcb) * 512);
            #pragma unroll
            for (int mf = 0; mf < 4; ++mf)
                #pragma unroll
                for (int nf = 0; nf < 4; ++nf)
                    acc[mf][nf] = __builtin_amdgcn_mfma_f32_16x16x32_bf16(
                        a[mf], bb[nf], acc[mf][nf], 0, 0, 0);
        }
    }

    // ReLU
    #pragma unroll
    for (int mf = 0; mf < 4; ++mf)
        #pragma unroll
        for (int nf = 0; nf < 4; ++nf)
            #pragma unroll
            for (int i = 0; i < 4; ++i)
                acc[mf][nf][i] = fmaxf(acc[mf][nf][i], 0.f);

    // LN cross-wave reduce
    #pragma unroll
    for (int mf = 0; mf < 4; ++mf) {
        #pragma unroll
        for (int i = 0; i < 4; ++i) {
            float s = acc[mf][0][i] + acc[mf][1][i] + acc[mf][2][i] + acc[mf][3][i];
            float q = acc[mf][0][i] * acc[mf][0][i] + acc[mf][1][i] * acc[mf][1][i] +
                      acc[mf][2][i] * acc[mf][2][i] + acc[mf][3][i] * acc[mf][3][i];
            #pragma unroll
            for (int off = 1; off < 16; off <<= 1) {
                s += __shfl_xor(s, off);
                q += __shfl_xor(q, off);
            }
            if (ln15 == 0) {
                const int row = 16 * mf + (lane >> 4) * 4 + i;
                red_s[row][wv] = s;
                red_q[row][wv] = q;
            }
        }
    }
    __syncthreads();
    if (tid < 64) {
        const float s = red_s[tid][0] + red_s[tid][1] + red_s[tid][2] + red_s[tid][3];
        const float q = red_q[tid][0] + red_q[tid][1] + red_q[tid][2] + red_q[tid][3];
        const float mean = s * (1.f / 256.f);
        const float var  = q * (1.f / 256.f) - mean * mean;
        ln_m[tid] = mean;
        ln_r[tid] = rsqrtf(var + 1e-5f);
    }
    __syncthreads();

    float gv[4], bev[4];
    #pragma unroll
    for (int nf = 0; nf < 4; ++nf) {
        const int col = wv * 64 + nf * 16 + ln15;
        gv[nf]  = args.g[pred][col];
        bev[nf] = args.be[pred][col];
    }

    if (!LIN) {
        bf16* ob = h1out + (size_t)pred * H1SZ + ((size_t)(b * SS + s0)) * HH;
        #pragma unroll
        for (int mf = 0; mf < 4; ++mf) {
            #pragma unroll
            for (int i = 0; i < 4; ++i) {
                const int row = 16 * mf + (lane >> 4) * 4 + i;
                const float mean = ln_m[row], rs = ln_r[row];
                #pragma unroll
                for (int nf = 0; nf < 4; ++nf) {
                    const float o = (acc[mf][nf][i] - mean) * rs * gv[nf] + bev[nf];
                    ob[(size_t)row * HH + wv * 64 + nf * 16 + ln15] = (bf16)o;
                }
            }
        }
    } else {
        float lwv[4];
        #pragma unroll
        for (int nf = 0; nf < 4; ++nf) lwv[nf] = args.lw[pred][wv * 64 + nf * 16 + ln15];
        const float lb0 = args.lb[pred][0];
        #pragma unroll
        for (int mf = 0; mf < 4; ++mf) {
            #pragma unroll
            for (int i = 0; i < 4; ++i) {
                const int row = 16 * mf + (lane >> 4) * 4 + i;
                const float mean = ln_m[row], rs = ln_r[row];
                float t = 0.f;
                #pragma unroll
                for (int nf = 0; nf < 4; ++nf)
                    t += ((acc[mf][nf][i] - mean) * rs * gv[nf] + bev[nf]) * lwv[nf];
                #pragma unroll
                for (int off = 1; off < 16; off <<= 1) t += __shfl_xor(t, off);
                if (ln15 == 0) red_s[row][wv] = t;
            }
        }
        __syncthreads();
        if (tid < 64) {
            const int gr = b * SS + s0 + tid;
            const float dv = red_s[tid][0] + red_s[tid][1] + red_s[tid][2] + red_s[tid][3] + lb0;
            args.out[pred][gr] = mask[gr] ? 0.f : dv;
        }
    }
}

// ---------------- duration cumsum + d_rounded + mel_len ----------------------
__global__ void dur_kernel(const int* __restrict__ dur, int* __restrict__ cum,
                           float* __restrict__ drnd, float* __restrict__ mlen) {
    __shared__ int sb[SS];
    const int b = blockIdx.x, t = threadIdx.x;
    const int v = dur[b * SS + t];
    drnd[b * SS + t] = (float)v;
    sb[t] = v;
    __syncthreads();
    for (int off = 1; off < SS; off <<= 1) {
        const int add = (t >= off) ? sb[t - off] : 0;
        __syncthreads();
        sb[t] += add;
        __syncthreads();
    }
    cum[b * SS + t] = sb[t];
    if (t == SS - 1) mlen[b] = (float)sb[t];
}

// ---------------- length regulator (f32, recomputes x + p_emb + e_emb) ------
__global__ __launch_bounds__(256) void gather_kernel(
    const float* __restrict__ x,
    const float* __restrict__ ptab, const float* __restrict__ pt,
    const float* __restrict__ etab, const float* __restrict__ et,
    const int* __restrict__ cum, float* __restrict__ mel)
{
    const int row  = blockIdx.x * 4 + (threadIdx.x >> 6);   // b*T + t
    const int lane = threadIdx.x & 63;
    const int b = row >> 11;
    const int t = row & (TT - 1);
    const int* cb = cum + b * SS;
    const int ml = cb[SS - 1];
    float4 v = make_float4(0.f, 0.f, 0.f, 0.f);
    if (t < ml) {
        int lo = 0, hi = SS;
        while (lo < hi) { int mid = (lo + hi) >> 1; if (cb[mid] <= t) lo = mid + 1; else hi = mid; }
        const int idx = min(lo, SS - 1);
        const size_t src = ((size_t)b * SS + idx) * HH + lane * 4;
        v = *(const float4*)(x + src);
        const int pb = bucket256(pt[b * SS + idx]);
        const int eb = bucket256(et[b * SS + idx]);
        const float4 pv = *(const float4*)(ptab + (size_t)pb * HH + lane * 4);
        const float4 ev = *(const float4*)(etab + (size_t)eb * HH + lane * 4);
        v.x += pv.x + ev.x; v.y += pv.y + ev.y; v.z += pv.z + ev.z; v.w += pv.w + ev.w;
    }
    *(float4*)(mel + (size_t)row * HH + lane * 4) = v;
}

// ---------------- launch -----------------------------------------------------
extern "C" void kernel_launch(void* const* d_in, const int* in_sizes, int n_in,
                              void* d_out, int out_size, void* d_ws, size_t ws_size,
                              hipStream_t stream) {
    (void)in_sizes; (void)n_in; (void)out_size; (void)ws_size;

    const float*   x      = (const float*)d_in[0];
    const float*   pitch  = (const float*)d_in[1];
    const float*   energy = (const float*)d_in[2];
    const uint8_t* mask   = (const uint8_t*)d_in[3];
    const int*     dur    = (const int*)d_in[4];
    const float*   ptab   = (const float*)d_in[36];
    const float*   etab   = (const float*)d_in[37];

    float* out = (float*)d_out;
    const size_t N_MEL = (size_t)BB * TT * HH;
    float* out_p  = out + N_MEL;
    float* out_e  = out_p + (size_t)BB * SS;
    float* out_ld = out_e + (size_t)BB * SS;
    float* out_dr = out_ld + (size_t)BB * SS;
    float* out_ml = out_dr + (size_t)BB * SS;

    // ws: packed weights (6*3*256*256 bf16 = 2.25MB) | cum (B*S int)
    bf16* wpk = (bf16*)d_ws;
    int*  cum = (int*)(wpk + 6 * WSZ);

    // h1 buffers (3 x 16MB bf16 = 48MB) live in the mel output region —
    // dead by the time gather_kernel (the last kernel) overwrites all of mel.
    bf16* h1 = (bf16*)out;

    wt_pack<<<18, 256, 0, stream>>>(
        (const float*)d_in[6],  (const float*)d_in[10],   // d: w1, w2
        (const float*)d_in[16], (const float*)d_in[20],   // p: w1, w2
        (const float*)d_in[26], (const float*)d_in[30],   // e: w1, w2
        wpk);
    dur_kernel<<<BB, SS, 0, stream>>>(dur, cum, out_dr, out_ml);

    Args3 a1 = {
        {(const float*)d_in[7],  (const float*)d_in[17], (const float*)d_in[27]},  // b1
        {(const float*)d_in[8],  (const float*)d_in[18], (const float*)d_in[28]},  // g1
        {(const float*)d_in[9],  (const float*)d_in[19], (const float*)d_in[29]},  // be1
        {nullptr, nullptr, nullptr}, {nullptr, nullptr, nullptr},
        {nullptr, nullptr, nullptr}
    };
    Args3 a2 = {
        {(const float*)d_in[11], (const float*)d_in[21], (const float*)d_in[31]},  // b2
        {(const float*)d_in[12], (const float*)d_in[22], (const float*)d_in[32]},  // g2
        {(const float*)d_in[13], (const float*)d_in[23], (const float*)d_in[33]},  // be2
        {(const float*)d_in[14], (const float*)d_in[24], (const float*)d_in[34]},  // lw
        {(const float*)d_in[15], (const float*)d_in[25], (const float*)d_in[35]},  // lb
        {out_ld, out_p, out_e}
    };

    conv_all<false><<<3 * 512, 256, 0, stream>>>(x, ptab, pitch, wpk, a1, h1, nullptr);
    conv_all<true ><<<3 * 512, 256, 0, stream>>>(h1, nullptr, nullptr, wpk, a2, nullptr, mask);

    gather_kernel<<<(BB * TT) / 4, 256, 0, stream>>>(x, ptab, pitch, etab, energy, cum, out);
}

// Round 4
// 164.271 us; speedup vs baseline: 6.5127x; 1.0094x over previous
//
#include <hip/hip_runtime.h>
#include <cstdint>
#include <cstddef>

// VarianceAdaptor — R4: software-pipelined flat K-loop (depth-2 prefetch),
// scatter-precomputed length-regulator index, grid-stride gather.
// B=64, S=512, T=2048, H=F=256, K=3, NBINS=256.

#define HH 256
#define SS 512
#define BB 64
#define TT 2048

typedef __bf16 bf16;
typedef __attribute__((ext_vector_type(8))) __bf16 bf16x8;
typedef __attribute__((ext_vector_type(4))) __bf16 bf16x4;
typedef __attribute__((ext_vector_type(4))) float f32x4;

static constexpr size_t WSZ  = (size_t)3 * HH * HH;   // elems per conv weight
static constexpr size_t H1SZ = (size_t)BB * SS * HH;  // elems per h1 buffer

// swizzled halfword index into a [rows][256] bf16 LDS tile (row stride 512B).
__device__ __forceinline__ int swz(int r, int c) { return (r * HH + c) ^ ((r & 7) << 3); }

// ---------------- bucket (searchsorted over jnp.linspace(-2,2,255) edges) ----
__device__ __forceinline__ float edge_val(int j) {
    const float step = 4.0f / 254.0f;
    if (j == 254) return 2.0f;
    return __fadd_rn(-2.0f, __fmul_rn((float)j, step));
}
__device__ __forceinline__ int bucket256(float v) {
    int lo = 0, hi = 255;
    while (lo < hi) {
        int mid = (lo + hi) >> 1;
        if (edge_val(mid) < v) lo = mid + 1; else hi = mid;
    }
    return lo;
}

// ------------- weight pack: w[k][c][f] f32 -> wp[k][fb][kcb][lane][8] bf16 ---
__global__ void wt_pack(const float* __restrict__ w0, const float* __restrict__ w1,
                        const float* __restrict__ w2, const float* __restrict__ w3,
                        const float* __restrict__ w4, const float* __restrict__ w5,
                        bf16* __restrict__ wp) {
    const int cv = blockIdx.x / 3, k = blockIdx.x % 3;
    const float* wsel[6] = {w0, w1, w2, w3, w4, w5};
    const float* wk = wsel[cv] + (size_t)k * HH * HH;   // [c][f]
    bf16* o = wp + ((size_t)(cv * 3 + k)) * HH * HH;
    for (int fb = 0; fb < 16; ++fb) {
        #pragma unroll
        for (int h = 0; h < 2; ++h) {
            const int idx  = threadIdx.x + 256 * h;     // 0..511
            const int kcb  = idx >> 6, lane = idx & 63;
            const int f    = fb * 16 + (lane & 15);
            const int c0   = kcb * 32 + (lane >> 4) * 8;
            bf16x8 v;
            #pragma unroll
            for (int j = 0; j < 8; ++j) v[j] = (bf16)wk[(size_t)(c0 + j) * HH + f];
            *(bf16x8*)(o + (((size_t)fb * 8 + kcb) * 64 + lane) * 8) = v;
        }
    }
}

// ---------------- merged fused conv (3 predictors in one grid) ---------------
struct Args3 {
    const float* bias[3];
    const float* g[3];
    const float* be[3];
    const float* lw[3];
    const float* lb[3];
    float*       out[3];
};

template <bool LIN>
__global__ __launch_bounds__(256, 3) void conv_all(
    const void* __restrict__ in,      // !LIN: x f32 ; LIN: h1 base bf16
    const float* __restrict__ tab,    // p_table (pred 2, !LIN)
    const float* __restrict__ tgt,    // pitch_target
    const bf16* __restrict__ wpk,     // packed weights, 6 convs
    Args3 args,
    bf16* __restrict__ h1out,         // !LIN output base
    const uint8_t* __restrict__ mask) // LIN only
{
    __shared__ alignas(16) bf16 tile[66 * HH];
    __shared__ float red_s[64][4], red_q[64][4];
    __shared__ float ln_m[64], ln_r[64];
    __shared__ int remb[66];

    const int tid    = threadIdx.x;
    const int pred   = blockIdx.x >> 9;
    const int within = blockIdx.x & 511;
    const int b      = within >> 3;
    const int s0     = (within & 7) * 64;
    const bool emb   = (!LIN) && (pred == 2);

    if (emb) {
        if (tid < 66) {
            int s = s0 - 1 + tid;
            remb[tid] = (s >= 0 && s < SS) ? bucket256(tgt[b * SS + s]) : 0;
        }
        __syncthreads();
    }

    if (!LIN) {
        const float* inb = (const float*)in + (size_t)b * SS * HH;
        for (int idx = tid; idx < 66 * 64; idx += 256) {
            const int r = idx >> 6, c4 = (idx & 63) << 2;
            const int s = s0 - 1 + r;
            float4 v = make_float4(0.f, 0.f, 0.f, 0.f);
            if (s >= 0 && s < SS) {
                v = *(const float4*)(inb + (size_t)s * HH + c4);
                if (emb) {
                    const float4 tv = *(const float4*)(tab + (size_t)remb[r] * HH + c4);
                    v.x += tv.x; v.y += tv.y; v.z += tv.z; v.w += tv.w;
                }
            }
            bf16x4 bv = {(bf16)v.x, (bf16)v.y, (bf16)v.z, (bf16)v.w};
            *(bf16x4*)&tile[swz(r, c4)] = bv;
        }
    } else {
        const bf16* inb = (const bf16*)in + (size_t)pred * H1SZ + (size_t)b * SS * HH;
        for (int idx = tid; idx < 66 * 32; idx += 256) {
            const int r = idx >> 5, c8 = (idx & 31) << 3;
            const int s = s0 - 1 + r;
            bf16x8 v = {};
            if (s >= 0 && s < SS) v = *(const bf16x8*)(inb + (size_t)s * HH + c8);
            *(bf16x8*)&tile[swz(r, c8)] = v;
        }
    }
    __syncthreads();

    const int lane = tid & 63;
    const int wv   = tid >> 6;
    const int ln15 = lane & 15;
    const int g8   = (lane >> 4) << 3;

    const bf16* wt = wpk + (size_t)(pred * 2 + (LIN ? 1 : 0)) * WSZ;

    f32x4 acc[4][4];
    #pragma unroll
    for (int nf = 0; nf < 4; ++nf) {
        const float bv = args.bias[pred][wv * 64 + nf * 16 + ln15];
        #pragma unroll
        for (int mf = 0; mf < 4; ++mf) acc[mf][nf] = f32x4{bv, bv, bv, bv};
    }

    // ---- flat 24-step K-loop, explicit depth-2 software pipeline ----
    bf16x8 a0[4], b0[4], a1[4], b1[4];

#define LOADSTEP(A_, B_, T_) do {                                              \
    const int k_ = (T_) >> 3, kcb_ = (T_) & 7;                                 \
    const int kc_ = kcb_ << 5;                                                 \
    const int ar_ = ln15 + k_;                                                 \
    _Pragma("unroll")                                                          \
    for (int mf_ = 0; mf_ < 4; ++mf_)                                          \
        A_[mf_] = *(const bf16x8*)&tile[swz(16 * mf_ + ar_, kc_ + g8)];        \
    const bf16* bp_ = wt + ((((size_t)k_ * 16 + wv * 4) * 8 + kcb_) << 9)      \
                         + (size_t)lane * 8;                                   \
    _Pragma("unroll")                                                          \
    for (int nf_ = 0; nf_ < 4; ++nf_)                                          \
        B_[nf_] = *(const bf16x8*)(bp_ + ((size_t)nf_ << 12));                 \
} while (0)

#define MFMASTEP(A_, B_) do {                                                  \
    _Pragma("unroll")                                                          \
    for (int mf_ = 0; mf_ < 4; ++mf_)                                          \
        _Pragma("unroll")                                                      \
        for (int nf_ = 0; nf_ < 4; ++nf_)                                      \
            acc[mf_][nf_] = __builtin_amdgcn_mfma_f32_16x16x32_bf16(           \
                A_[mf_], B_[nf_], acc[mf_][nf_], 0, 0, 0);                     \
} while (0)

    LOADSTEP(a0, b0, 0);
    #pragma unroll 1
    for (int t2 = 0; t2 < 11; ++t2) {
        const int t = 2 * t2;
        LOADSTEP(a1, b1, t + 1);
        MFMASTEP(a0, b0);
        LOADSTEP(a0, b0, t + 2);
        MFMASTEP(a1, b1);
    }
    LOADSTEP(a1, b1, 23);
    MFMASTEP(a0, b0);
    MFMASTEP(a1, b1);

#undef LOADSTEP
#undef MFMASTEP

    // ReLU
    #pragma unroll
    for (int mf = 0; mf < 4; ++mf)
        #pragma unroll
        for (int nf = 0; nf < 4; ++nf)
            #pragma unroll
            for (int i = 0; i < 4; ++i)
                acc[mf][nf][i] = fmaxf(acc[mf][nf][i], 0.f);

    // LN cross-wave reduce
    #pragma unroll
    for (int mf = 0; mf < 4; ++mf) {
        #pragma unroll
        for (int i = 0; i < 4; ++i) {
            float s = acc[mf][0][i] + acc[mf][1][i] + acc[mf][2][i] + acc[mf][3][i];
            float q = acc[mf][0][i] * acc[mf][0][i] + acc[mf][1][i] * acc[mf][1][i] +
                      acc[mf][2][i] * acc[mf][2][i] + acc[mf][3][i] * acc[mf][3][i];
            #pragma unroll
            for (int off = 1; off < 16; off <<= 1) {
                s += __shfl_xor(s, off);
                q += __shfl_xor(q, off);
            }
            if (ln15 == 0) {
                const int row = 16 * mf + (lane >> 4) * 4 + i;
                red_s[row][wv] = s;
                red_q[row][wv] = q;
            }
        }
    }
    __syncthreads();
    if (tid < 64) {
        const float s = red_s[tid][0] + red_s[tid][1] + red_s[tid][2] + red_s[tid][3];
        const float q = red_q[tid][0] + red_q[tid][1] + red_q[tid][2] + red_q[tid][3];
        const float mean = s * (1.f / 256.f);
        const float var  = q * (1.f / 256.f) - mean * mean;
        ln_m[tid] = mean;
        ln_r[tid] = rsqrtf(var + 1e-5f);
    }
    __syncthreads();

    float gv[4], bev[4];
    #pragma unroll
    for (int nf = 0; nf < 4; ++nf) {
        const int col = wv * 64 + nf * 16 + ln15;
        gv[nf]  = args.g[pred][col];
        bev[nf] = args.be[pred][col];
    }

    if (!LIN) {
        bf16* ob = h1out + (size_t)pred * H1SZ + ((size_t)(b * SS + s0)) * HH;
        #pragma unroll
        for (int mf = 0; mf < 4; ++mf) {
            #pragma unroll
            for (int i = 0; i < 4; ++i) {
                const int row = 16 * mf + (lane >> 4) * 4 + i;
                const float mean = ln_m[row], rs = ln_r[row];
                #pragma unroll
                for (int nf = 0; nf < 4; ++nf) {
                    const float o = (acc[mf][nf][i] - mean) * rs * gv[nf] + bev[nf];
                    ob[(size_t)row * HH + wv * 64 + nf * 16 + ln15] = (bf16)o;
                }
            }
        }
    } else {
        float lwv[4];
        #pragma unroll
        for (int nf = 0; nf < 4; ++nf) lwv[nf] = args.lw[pred][wv * 64 + nf * 16 + ln15];
        const float lb0 = args.lb[pred][0];
        #pragma unroll
        for (int mf = 0; mf < 4; ++mf) {
            #pragma unroll
            for (int i = 0; i < 4; ++i) {
                const int row = 16 * mf + (lane >> 4) * 4 + i;
                const float mean = ln_m[row], rs = ln_r[row];
                float t = 0.f;
                #pragma unroll
                for (int nf = 0; nf < 4; ++nf)
                    t += ((acc[mf][nf][i] - mean) * rs * gv[nf] + bev[nf]) * lwv[nf];
                #pragma unroll
                for (int off = 1; off < 16; off <<= 1) t += __shfl_xor(t, off);
                if (ln15 == 0) red_s[row][wv] = t;
            }
        }
        __syncthreads();
        if (tid < 64) {
            const int gr = b * SS + s0 + tid;
            const float dv = red_s[tid][0] + red_s[tid][1] + red_s[tid][2] + red_s[tid][3] + lb0;
            args.out[pred][gr] = mask[gr] ? 0.f : dv;
        }
    }
}

// ------- duration cumsum + d_rounded + mel_len + scatter expansion index -----
__global__ void dur_kernel(const int* __restrict__ dur, int* __restrict__ idxb,
                           int* __restrict__ mli,
                           float* __restrict__ drnd, float* __restrict__ mlen) {
    __shared__ int sb[SS];
    const int b = blockIdx.x, t = threadIdx.x;
    const int v = dur[b * SS + t];
    drnd[b * SS + t] = (float)v;
    sb[t] = v;
    __syncthreads();
    for (int off = 1; off < SS; off <<= 1) {
        const int add = (t >= off) ? sb[t - off] : 0;
        __syncthreads();
        sb[t] += add;
        __syncthreads();
    }
    const int hi = sb[t];
    const int lo = hi - v;
    for (int j = lo; j < hi; ++j) idxb[b * TT + j] = t;   // disjoint ranges
    if (t == SS - 1) { mlen[b] = (float)hi; mli[b] = hi; }
}

// ---------------- length regulator (precomputed idx, grid-stride) ------------
__global__ __launch_bounds__(256) void gather_kernel(
    const float* __restrict__ x,
    const float* __restrict__ ptab, const float* __restrict__ pt,
    const float* __restrict__ etab, const float* __restrict__ et,
    const int* __restrict__ idxb, const int* __restrict__ mli,
    float* __restrict__ mel)
{
    const int lane = threadIdx.x & 63;
    for (int row = blockIdx.x * 4 + (threadIdx.x >> 6); row < BB * TT; row += 4096 * 4) {
        const int b = row >> 11;
        const int t = row & (TT - 1);
        float4 v = make_float4(0.f, 0.f, 0.f, 0.f);
        if (t < mli[b]) {
            const int idx = idxb[row];
            const size_t src = ((size_t)b * SS + idx) * HH + lane * 4;
            v = *(const float4*)(x + src);
            const int pb = bucket256(pt[b * SS + idx]);
            const int eb = bucket256(et[b * SS + idx]);
            const float4 pv = *(const float4*)(ptab + (size_t)pb * HH + lane * 4);
            const float4 ev = *(const float4*)(etab + (size_t)eb * HH + lane * 4);
            v.x += pv.x + ev.x; v.y += pv.y + ev.y; v.z += pv.z + ev.z; v.w += pv.w + ev.w;
        }
        *(float4*)(mel + (size_t)row * HH + lane * 4) = v;
    }
}

// ---------------- launch -----------------------------------------------------
extern "C" void kernel_launch(void* const* d_in, const int* in_sizes, int n_in,
                              void* d_out, int out_size, void* d_ws, size_t ws_size,
                              hipStream_t stream) {
    (void)in_sizes; (void)n_in; (void)out_size; (void)ws_size;

    const float*   x      = (const float*)d_in[0];
    const float*   pitch  = (const float*)d_in[1];
    const float*   energy = (const float*)d_in[2];
    const uint8_t* mask   = (const uint8_t*)d_in[3];
    const int*     dur    = (const int*)d_in[4];
    const float*   ptab   = (const float*)d_in[36];
    const float*   etab   = (const float*)d_in[37];

    float* out = (float*)d_out;
    const size_t N_MEL = (size_t)BB * TT * HH;
    float* out_p  = out + N_MEL;
    float* out_e  = out_p + (size_t)BB * SS;
    float* out_ld = out_e + (size_t)BB * SS;
    float* out_dr = out_ld + (size_t)BB * SS;
    float* out_ml = out_dr + (size_t)BB * SS;

    // ws: packed weights (2.36 MB) | idxb (B*T int, 512 KB) | mli (64 int)
    bf16* wpk  = (bf16*)d_ws;
    int*  idxb = (int*)(wpk + 6 * WSZ);
    int*  mli  = idxb + (size_t)BB * TT;

    // h1 (3 x 16MB bf16) lives in the mel output region — dead by the time
    // gather_kernel (the last kernel) overwrites all of mel.
    bf16* h1 = (bf16*)out;

    wt_pack<<<18, 256, 0, stream>>>(
        (const float*)d_in[6],  (const float*)d_in[10],
        (const float*)d_in[16], (const float*)d_in[20],
        (const float*)d_in[26], (const float*)d_in[30],
        wpk);
    dur_kernel<<<BB, SS, 0, stream>>>(dur, idxb, mli, out_dr, out_ml);

    Args3 a1 = {
        {(const float*)d_in[7],  (const float*)d_in[17], (const float*)d_in[27]},
        {(const float*)d_in[8],  (const float*)d_in[18], (const float*)d_in[28]},
        {(const float*)d_in[9],  (const float*)d_in[19], (const float*)d_in[29]},
        {nullptr, nullptr, nullptr}, {nullptr, nullptr, nullptr},
        {nullptr, nullptr, nullptr}
    };
    Args3 a2 = {
        {(const float*)d_in[11], (const float*)d_in[21], (const float*)d_in[31]},
        {(const float*)d_in[12], (const float*)d_in[22], (const float*)d_in[32]},
        {(const float*)d_in[13], (const float*)d_in[23], (const float*)d_in[33]},
        {(const float*)d_in[14], (const float*)d_in[24], (const float*)d_in[34]},
        {(const float*)d_in[15], (const float*)d_in[25], (const float*)d_in[35]},
        {out_ld, out_p, out_e}
    };

    conv_all<false><<<3 * 512, 256, 0, stream>>>(x, ptab, pitch, wpk, a1, h1, nullptr);
    conv_all<true ><<<3 * 512, 256, 0, stream>>>(h1, nullptr, nullptr, wpk, a2, nullptr, mask);

    gather_kernel<<<4096, 256, 0, stream>>>(x, ptab, pitch, etab, energy, idxb, mli, out);
}